// Round 5
// baseline (161.096 us; speedup 1.0000x reference)
//
#include <hip/hip_runtime.h>
#include <math.h>

// CellList dense masked-distance map, N=6144, no PBC.
// out[i*N+j] = |r_i - r_j| if (i>j && species_i!=-1 && species_j!=-1 &&
//                              dist<=cutoff && sq>0) else 0.
//
// R10 = R9 with the nontemporal-store compile error fixed: the builtin
// requires a native vector type, not HIP_vector_type<float,4>. Uses clang
// ext_vector_type(4). Experiment unchanged:
// Post-mortem of R6/R7/R8: three different store schedules (interleaved /
// split / batched) all land at a 63+-1 us kernel slice, and R7's pure
// fill-clone ran at ~2.7 TB/s while rocclr's fill hits 6.6 on the same
// volume -- consistent with the kernel window being gated by L3 dirty-
// poison eviction drain ((256 MB backlog + 151 MB ours)/6.6 TB/s = 62 us).
// The ONE untested cell: no-allocate (nontemporal) stores on FULLY-FILLED
// contiguous lines. R4's nt experiment regressed, but it was confounded:
// R4's 32B-lane-stride stores made every nt write a 50%-filled line.
// R10 tests nt on the coalescing-correct structure: each wave store is a
// dense contiguous 1 KB segment of full 64B lines.
//  - 3072 blocks (12/CU); each block = one 2048-col strip x 6 consecutive
//    rows. j-side coords/species loaded ONCE per thread, reused across the
//    6 rows. Lane-contiguous store chunks (tid*4, +1024).
//  - compute all 6 rows into registers, then 12 nt float4 stores
//    back-to-back (sched_barrier pins the grouping).
//  - mask via sq <= T (T = largest f32 with sqrt_rn(T) <= cutoff) -- bit-
//    exact vs reference (absmax 0.0 in R2/R4/R6/R7/R8).
//  - dist via raw v_sqrt_f32 (1 ulp; threshold 0.1).
//  - sq in numpy's ((x*x + y*y) + z*z) order, no FMA contraction.

typedef float f32x4 __attribute__((ext_vector_type(4)));

constexpr int N      = 6144;
constexpr int BLOCK  = 256;
constexpr int CPB    = 2048;         // columns per block
constexpr int HALF   = CPB / 2;      // 1024: two contiguous 4-col chunks/thread
constexpr int NSTRIP = N / CPB;      // 3 column strips
constexpr int RPB    = 6;            // rows per block
constexpr int NROWG  = N / RPB;      // 1024 row groups

__global__ __launch_bounds__(BLOCK) void cell_list_kernel(
    const float* __restrict__ coords,   // [N][3] f32
    const int*   __restrict__ species,  // [N] i32
    const int*   __restrict__ cutoff_p, // [1] i32
    float*       __restrict__ out)      // [N][N] f32
{
    const int bx    = blockIdx.x;
    const int strip = bx % NSTRIP;
    const int i0    = (bx / NSTRIP) * RPB;
    const int base  = strip * CPB;
    const int jA    = base + (int)threadIdx.x * 4;  // chunk A: contiguous across wave
    const int jB    = jA + HALF;                    // chunk B: contiguous across wave

    // T = largest f32 x with sqrt_rn(x) <= c: sqrt_rn(x) <= c iff
    // sqrt_exact(x) < c + 0.5*ulp(c) (tie impossible: midpoint^2 not f32-
    // representable). Exact in double, rounded down. Scalar, once.
    const float  c  = (float)cutoff_p[0];
    const float  cn = __int_as_float(__float_as_int(c) + 1);
    const double md = (double)c + 0.5 * ((double)cn - (double)c);
    const double Td = md * md;
    float T = (float)Td;
    if ((double)T > Td) T = __int_as_float(__float_as_int(T) - 1);

    // Load j-side data once per thread iff any row in this block computes.
    float fA[12], fB[12];
    int   sA[4],  sB[4];
    const bool anyrow = (i0 + RPB - 1 > base);
    if (anyrow) {
        const float4* ca = reinterpret_cast<const float4*>(coords + 3 * (size_t)jA);
        const float4* cb = reinterpret_cast<const float4*>(coords + 3 * (size_t)jB);
#pragma unroll
        for (int q = 0; q < 3; ++q) {
            const float4 va = ca[q];
            fA[4 * q + 0] = va.x; fA[4 * q + 1] = va.y;
            fA[4 * q + 2] = va.z; fA[4 * q + 3] = va.w;
            const float4 vb = cb[q];
            fB[4 * q + 0] = vb.x; fB[4 * q + 1] = vb.y;
            fB[4 * q + 2] = vb.z; fB[4 * q + 3] = vb.w;
        }
        const int4 sa = *reinterpret_cast<const int4*>(species + jA);
        const int4 sb = *reinterpret_cast<const int4*>(species + jB);
        sA[0] = sa.x; sA[1] = sa.y; sA[2] = sa.z; sA[3] = sa.w;
        sB[0] = sb.x; sB[1] = sb.y; sB[2] = sb.z; sB[3] = sb.w;
    }

    // Compute all 6 rows into registers.
    float rA[RPB][4], rB[RPB][4];
#pragma unroll
    for (int rr = 0; rr < RPB; ++rr)
#pragma unroll
        for (int k = 0; k < 4; ++k) { rA[rr][k] = 0.0f; rB[rr][k] = 0.0f; }

#pragma unroll
    for (int rr = 0; rr < RPB; ++rr) {
        const int i = i0 + rr;
        if (i <= base) continue;            // whole strip j >= i: stay zero
        const int si = species[i];          // block-uniform -> scalar load
        if (si == -1) continue;             // dummy row: stay zero

        const float xi = coords[3 * i + 0];
        const float yi = coords[3 * i + 1];
        const float zi = coords[3 * i + 2];

#pragma unroll
        for (int k = 0; k < 4; ++k) {
            // Exact numpy order: (dx*dx + dy*dy) + dz*dz, no FMA.
            {
                const float dx = __fsub_rn(xi, fA[3 * k + 0]);
                const float dy = __fsub_rn(yi, fA[3 * k + 1]);
                const float dz = __fsub_rn(zi, fA[3 * k + 2]);
                const float sq = __fadd_rn(
                    __fadd_rn(__fmul_rn(dx, dx), __fmul_rn(dy, dy)),
                    __fmul_rn(dz, dz));
                const bool m = (sq <= T) && (sA[k] != -1) && (jA + k < i);
                rA[rr][k] = m ? __builtin_amdgcn_sqrtf(sq) : 0.0f;
            }
            {
                const float dx = __fsub_rn(xi, fB[3 * k + 0]);
                const float dy = __fsub_rn(yi, fB[3 * k + 1]);
                const float dz = __fsub_rn(zi, fB[3 * k + 2]);
                const float sq = __fadd_rn(
                    __fadd_rn(__fmul_rn(dx, dx), __fmul_rn(dy, dy)),
                    __fmul_rn(dz, dz));
                const bool m = (sq <= T) && (sB[k] != -1) && (jB + k < i);
                rB[rr][k] = m ? __builtin_amdgcn_sqrtf(sq) : 0.0f;
            }
        }
    }

    // Pin the compute/store grouping: all 12 stores issue back-to-back.
    __builtin_amdgcn_sched_barrier(0);

#pragma unroll
    for (int rr = 0; rr < RPB; ++rr) {
        const int i = i0 + rr;
        f32x4* ovA = reinterpret_cast<f32x4*>(out + (size_t)i * N + jA);
        f32x4* ovB = reinterpret_cast<f32x4*>(out + (size_t)i * N + jB);
        f32x4 va = { rA[rr][0], rA[rr][1], rA[rr][2], rA[rr][3] };
        f32x4 vb = { rB[rr][0], rB[rr][1], rB[rr][2], rB[rr][3] };
        __builtin_nontemporal_store(va, ovA);
        __builtin_nontemporal_store(vb, ovB);
    }
}

extern "C" void kernel_launch(void* const* d_in, const int* in_sizes, int n_in,
                              void* d_out, int out_size, void* d_ws, size_t ws_size,
                              hipStream_t stream) {
    // setup_inputs() order: species (i32 [1,N]), coordinates (f32 [1,N,3]),
    // cutoff (python int -> i32 [1]).
    const int*   species = (const int*)d_in[0];
    const float* coords  = (const float*)d_in[1];
    const int*   cutoff  = (const int*)d_in[2];
    float*       out     = (float*)d_out;

    dim3 block(BLOCK);
    dim3 grid(NSTRIP * NROWG);  // 3072 blocks = 12/CU
    hipLaunchKernelGGL(cell_list_kernel, grid, block, 0, stream,
                       coords, species, cutoff, out);
}

// Round 6
// 153.805 us; speedup vs baseline: 1.0474x; 1.0474x over previous
//
#include <hip/hip_runtime.h>
#include <math.h>

// CellList dense masked-distance map, N=6144, no PBC.
// out[i*N+j] = |r_i - r_j| if (i>j && species_i!=-1 && species_j!=-1 &&
//                              dist<=cutoff && sq>0) else 0.
//
// R11 = FINAL: revert to R8 (best measured, 155.3 us), closing the
// experiment matrix. Store-path variants all measured at 62-64 us kernel
// slice (dur minus the harness's ~91-101 us poison fill):
//   R6  interleaved cached stores        ~62 us slice
//   R7  split zero-fill + sparse compute ~68 us (serialization regressed)
//   R8  batched cached stores            ~64 us  <- best dur_us (155.3)
//   R10 batched nontemporal stores       ~62 us (neutral within noise)
// Conclusion: the kernel window is gated by HBM-draining the harness
// fill's dirty-L3 backlog (604 MB written at 6.6 TB/s immediately before
// us) plus our compulsory 151 MB output: (~256 MB backlog + 151 MB) /
// 6.6 TB/s = 62 us, invariant to store schedule and cache policy.
// Compute is ~4 us of VALU; inputs are ~100 KB. No in-kernel lever
// remains: this is the effective memory roofline for this harness.
//  - 3072 blocks (12/CU); each block = one 2048-col strip x 6 consecutive
//    rows. j-side coords/species loaded ONCE per thread, reused across the
//    6 rows. Lane-contiguous store chunks (tid*4, +1024): every wave
//    store is a dense contiguous 1 KB segment of full 64 B lines.
//  - compute all 6 rows into registers, then 12 float4 stores
//    back-to-back (sched_barrier pins the grouping).
//  - upper-triangle / dummy rows: result regs stay zero, stored in batch.
//  - mask via sq <= T (T = largest f32 with sqrt_rn(T) <= cutoff) -- bit-
//    exact vs reference (absmax 0.0 in R2/R4/R6/R7/R8/R10).
//  - dist via raw v_sqrt_f32 (1 ulp; threshold 0.1).
//  - sq in numpy's ((x*x + y*y) + z*z) order, no FMA contraction.

constexpr int N      = 6144;
constexpr int BLOCK  = 256;
constexpr int CPB    = 2048;         // columns per block
constexpr int HALF   = CPB / 2;      // 1024: two contiguous 4-col chunks/thread
constexpr int NSTRIP = N / CPB;      // 3 column strips
constexpr int RPB    = 6;            // rows per block
constexpr int NROWG  = N / RPB;      // 1024 row groups

__global__ __launch_bounds__(BLOCK) void cell_list_kernel(
    const float* __restrict__ coords,   // [N][3] f32
    const int*   __restrict__ species,  // [N] i32
    const int*   __restrict__ cutoff_p, // [1] i32
    float*       __restrict__ out)      // [N][N] f32
{
    const int bx    = blockIdx.x;
    const int strip = bx % NSTRIP;
    const int i0    = (bx / NSTRIP) * RPB;
    const int base  = strip * CPB;
    const int jA    = base + (int)threadIdx.x * 4;  // chunk A: contiguous across wave
    const int jB    = jA + HALF;                    // chunk B: contiguous across wave

    // T = largest f32 x with sqrt_rn(x) <= c: sqrt_rn(x) <= c iff
    // sqrt_exact(x) < c + 0.5*ulp(c) (tie impossible: midpoint^2 not f32-
    // representable). Exact in double, rounded down. Scalar, once.
    const float  c  = (float)cutoff_p[0];
    const float  cn = __int_as_float(__float_as_int(c) + 1);
    const double md = (double)c + 0.5 * ((double)cn - (double)c);
    const double Td = md * md;
    float T = (float)Td;
    if ((double)T > Td) T = __int_as_float(__float_as_int(T) - 1);

    // Load j-side data once per thread iff any row in this block computes.
    float fA[12], fB[12];
    int   sA[4],  sB[4];
    const bool anyrow = (i0 + RPB - 1 > base);
    if (anyrow) {
        const float4* ca = reinterpret_cast<const float4*>(coords + 3 * (size_t)jA);
        const float4* cb = reinterpret_cast<const float4*>(coords + 3 * (size_t)jB);
#pragma unroll
        for (int q = 0; q < 3; ++q) {
            const float4 va = ca[q];
            fA[4 * q + 0] = va.x; fA[4 * q + 1] = va.y;
            fA[4 * q + 2] = va.z; fA[4 * q + 3] = va.w;
            const float4 vb = cb[q];
            fB[4 * q + 0] = vb.x; fB[4 * q + 1] = vb.y;
            fB[4 * q + 2] = vb.z; fB[4 * q + 3] = vb.w;
        }
        const int4 sa = *reinterpret_cast<const int4*>(species + jA);
        const int4 sb = *reinterpret_cast<const int4*>(species + jB);
        sA[0] = sa.x; sA[1] = sa.y; sA[2] = sa.z; sA[3] = sa.w;
        sB[0] = sb.x; sB[1] = sb.y; sB[2] = sb.z; sB[3] = sb.w;
    }

    // Compute all 6 rows into registers.
    float rA[RPB][4], rB[RPB][4];
#pragma unroll
    for (int rr = 0; rr < RPB; ++rr)
#pragma unroll
        for (int k = 0; k < 4; ++k) { rA[rr][k] = 0.0f; rB[rr][k] = 0.0f; }

#pragma unroll
    for (int rr = 0; rr < RPB; ++rr) {
        const int i = i0 + rr;
        if (i <= base) continue;            // whole strip j >= i: stay zero
        const int si = species[i];          // block-uniform -> scalar load
        if (si == -1) continue;             // dummy row: stay zero

        const float xi = coords[3 * i + 0];
        const float yi = coords[3 * i + 1];
        const float zi = coords[3 * i + 2];

#pragma unroll
        for (int k = 0; k < 4; ++k) {
            // Exact numpy order: (dx*dx + dy*dy) + dz*dz, no FMA.
            {
                const float dx = __fsub_rn(xi, fA[3 * k + 0]);
                const float dy = __fsub_rn(yi, fA[3 * k + 1]);
                const float dz = __fsub_rn(zi, fA[3 * k + 2]);
                const float sq = __fadd_rn(
                    __fadd_rn(__fmul_rn(dx, dx), __fmul_rn(dy, dy)),
                    __fmul_rn(dz, dz));
                const bool m = (sq <= T) && (sA[k] != -1) && (jA + k < i);
                rA[rr][k] = m ? __builtin_amdgcn_sqrtf(sq) : 0.0f;
            }
            {
                const float dx = __fsub_rn(xi, fB[3 * k + 0]);
                const float dy = __fsub_rn(yi, fB[3 * k + 1]);
                const float dz = __fsub_rn(zi, fB[3 * k + 2]);
                const float sq = __fadd_rn(
                    __fadd_rn(__fmul_rn(dx, dx), __fmul_rn(dy, dy)),
                    __fmul_rn(dz, dz));
                const bool m = (sq <= T) && (sB[k] != -1) && (jB + k < i);
                rB[rr][k] = m ? __builtin_amdgcn_sqrtf(sq) : 0.0f;
            }
        }
    }

    // Pin the compute/store grouping: all 12 stores issue back-to-back,
    // fill-style.
    __builtin_amdgcn_sched_barrier(0);

#pragma unroll
    for (int rr = 0; rr < RPB; ++rr) {
        const int i = i0 + rr;
        float4* ovA = reinterpret_cast<float4*>(out + (size_t)i * N + jA);
        float4* ovB = reinterpret_cast<float4*>(out + (size_t)i * N + jB);
        *ovA = make_float4(rA[rr][0], rA[rr][1], rA[rr][2], rA[rr][3]);
        *ovB = make_float4(rB[rr][0], rB[rr][1], rB[rr][2], rB[rr][3]);
    }
}

extern "C" void kernel_launch(void* const* d_in, const int* in_sizes, int n_in,
                              void* d_out, int out_size, void* d_ws, size_t ws_size,
                              hipStream_t stream) {
    // setup_inputs() order: species (i32 [1,N]), coordinates (f32 [1,N,3]),
    // cutoff (python int -> i32 [1]).
    const int*   species = (const int*)d_in[0];
    const float* coords  = (const float*)d_in[1];
    const int*   cutoff  = (const int*)d_in[2];
    float*       out     = (float*)d_out;

    dim3 block(BLOCK);
    dim3 grid(NSTRIP * NROWG);  // 3072 blocks = 12/CU
    hipLaunchKernelGGL(cell_list_kernel, grid, block, 0, stream,
                       coords, species, cutoff, out);
}